// Round 1
// baseline (28742.593 us; speedup 1.0000x reference)
//
#include <hip/hip_runtime.h>
#include <math.h>

// LSTMModel: 2048 sequential steps, 2x LSTMCell(hidden=512), LN(64) front, fc(512->1).
// Strategy: precompute LN + Wih0@x for all t in parallel; persistent-grid recurrent
// kernel with all weights in REGISTERS (48 f32/thread across 128 blocks x 512 thr),
// flag-counter sync (device-scope atomics) between steps.

#define H      512
#define G4     2048
#define WIN    64
#define STEPS  2048
#define KBLK   128      // recurrent blocks (each owns 4 hidden units per layer)
#define TPB    512      // threads per recurrent block
#define UPB    4        // units per block

__device__ __forceinline__ float sigf(float x)      { return 1.0f / (1.0f + __expf(-x)); }
__device__ __forceinline__ float tanhfast(float x)  { return 2.0f / (1.0f + __expf(-2.0f * x)) - 1.0f; }

// ---------------- LayerNorm over sliding windows (parallel over t) ----------------
__global__ void ln_kernel(const float* __restrict__ batch, const float* __restrict__ lnw,
                          const float* __restrict__ lnb, float* __restrict__ lnx) {
    int wave = threadIdx.x >> 6;            // 4 waves/block, one t per wave
    int lane = threadIdx.x & 63;
    int t = blockIdx.x * 4 + wave;
    int src = t - 63 + lane;
    float v = (src >= 0) ? batch[src] : 0.0f;
    float s = v, ss = v * v;
    #pragma unroll
    for (int m = 32; m >= 1; m >>= 1) { s += __shfl_xor(s, m); ss += __shfl_xor(ss, m); }
    float mu   = s * (1.0f / 64.0f);
    float var  = ss * (1.0f / 64.0f) - mu * mu;   // biased variance
    float rstd = rsqrtf(var + 1e-5f);
    lnx[t * WIN + lane] = (v - mu) * rstd * lnw[lane] + lnb[lane];
}

// ------------- precomp0[t][r] = Wih0[r,:] . lnx[t,:] + bih0[r] + bhh0[r] ----------
__global__ __launch_bounds__(256) void precomp_kernel(
    const float* __restrict__ Wih0, const float* __restrict__ bih0,
    const float* __restrict__ bhh0, const float* __restrict__ lnx,
    float* __restrict__ pre) {
    __shared__ float Wt[64][65];   // +1 pad: lane-varying row reads conflict-free
    __shared__ float Xt[64][64];   // broadcast reads, no pad needed
    int r0 = blockIdx.x * 64;
    int t0 = blockIdx.y * 64;
    for (int i = threadIdx.x; i < 4096; i += 256) Wt[i >> 6][i & 63] = Wih0[r0 * 64 + i];
    for (int i = threadIdx.x; i < 4096; i += 256) Xt[i >> 6][i & 63] = lnx[t0 * 64 + i];
    __syncthreads();
    int lane = threadIdx.x & 63;
    int wv   = threadIdx.x >> 6;             // 0..3
    int row  = r0 + lane;
    float bias = bih0[row] + bhh0[row];
    for (int j = 0; j < 16; ++j) {
        int tl = wv * 16 + j;
        float acc = bias;
        #pragma unroll 8
        for (int k = 0; k < 64; ++k) acc += Wt[lane][k] * Xt[tl][k];
        pre[(size_t)(t0 + tl) * G4 + row] = acc;
    }
}

// ---------------- persistent recurrent kernel ----------------
__global__ __launch_bounds__(TPB) void recur_kernel(
    const float* __restrict__ Whh0,
    const float* __restrict__ Wih1, const float* __restrict__ Whh1,
    const float* __restrict__ bih1, const float* __restrict__ bhh1,
    const float* __restrict__ fcw,  const float* __restrict__ pre,
    float* h0buf, float* h1buf,     // [2][H] double buffers
    int* cnt0, int* cnt1,           // per-step completion counters
    float* __restrict__ pout) {     // [STEPS][KBLK] output partials
    const int tid   = threadIdx.x;
    const int b     = blockIdx.x;
    const int group = tid >> 5;     // 16 groups of 32 lanes; group = (gate<<2)|unit
    const int s     = tid & 31;
    const int g     = group >> 2;   // gate index 0..3 (i,f,g,o)
    const int ul    = group & 3;    // unit-in-block
    const int u0    = b * UPB;
    const int row   = g * H + u0 + ul;

    __shared__ float hA[H];         // h0(t-1), then h0(t)
    __shared__ float hB[H];         // h1(t-1)
    __shared__ float glds[16];
    __shared__ float h1n[UPB];

    // weights resident in registers for the whole 2048-step loop
    float w0[16], w1[16], w2[16];
    #pragma unroll
    for (int i = 0; i < 16; ++i) w0[i] = Whh0[(size_t)row * H + i * 32 + s];
    #pragma unroll
    for (int i = 0; i < 16; ++i) w1[i] = Wih1[(size_t)row * H + i * 32 + s];
    #pragma unroll
    for (int i = 0; i < 16; ++i) w2[i] = Whh1[(size_t)row * H + i * 32 + s];
    float bias1 = bih1[row] + bhh1[row];
    float fw0 = 0.f, fw1 = 0.f, fw2 = 0.f, fw3 = 0.f;
    if (tid == 0) { fw0 = fcw[u0]; fw1 = fcw[u0 + 1]; fw2 = fcw[u0 + 2]; fw3 = fcw[u0 + 3]; }
    float c0 = 0.0f, c1 = 0.0f;

    for (int t = 0; t < STEPS; ++t) {
        const int cur = t & 1, prv = cur ^ 1;
        // wait: h0(t-1) fully written AND all blocks done reading h0buf[cur] (as h0(t-2))
        if (t > 0 && tid == 0) {
            while (__hip_atomic_load(&cnt0[t - 1], __ATOMIC_ACQUIRE, __HIP_MEMORY_SCOPE_AGENT) < KBLK)
                __builtin_amdgcn_s_sleep(1);
        }
        __syncthreads();
        float pc = pre[(size_t)t * G4 + row];   // same addr across the 32-lane group (broadcast)
        hA[tid] = __hip_atomic_load(&h0buf[prv * H + tid], __ATOMIC_RELAXED, __HIP_MEMORY_SCOPE_AGENT);
        __syncthreads();

        // ---- layer 0: gates = precomp + Whh0 @ h0(t-1) ----
        float acc = 0.0f;
        #pragma unroll
        for (int i = 0; i < 16; ++i) acc += w0[i] * hA[i * 32 + s];
        #pragma unroll
        for (int m = 16; m >= 1; m >>= 1) acc += __shfl_xor(acc, m);
        if (s == 0) glds[group] = acc + pc;
        __syncthreads();
        if (tid < UPB) {
            float iv = sigf(glds[tid]);
            float fv = sigf(glds[4 + tid]);
            float gv = tanhfast(glds[8 + tid]);
            float ov = sigf(glds[12 + tid]);
            c0 = fv * c0 + iv * gv;
            float h = ov * tanhfast(c0);
            __hip_atomic_store(&h0buf[cur * H + u0 + tid], h, __ATOMIC_RELEASE, __HIP_MEMORY_SCOPE_AGENT);
        }
        __syncthreads();
        if (tid == 0)
            __hip_atomic_fetch_add(&cnt0[t], 1, __ATOMIC_RELEASE, __HIP_MEMORY_SCOPE_AGENT);

        // wait: full h0(t) and h1(t-1)
        if (tid == 0) {
            while (__hip_atomic_load(&cnt0[t], __ATOMIC_ACQUIRE, __HIP_MEMORY_SCOPE_AGENT) < KBLK)
                __builtin_amdgcn_s_sleep(1);
            if (t > 0)
                while (__hip_atomic_load(&cnt1[t - 1], __ATOMIC_ACQUIRE, __HIP_MEMORY_SCOPE_AGENT) < KBLK)
                    __builtin_amdgcn_s_sleep(1);
        }
        __syncthreads();
        hA[tid] = __hip_atomic_load(&h0buf[cur * H + tid], __ATOMIC_RELAXED, __HIP_MEMORY_SCOPE_AGENT);
        hB[tid] = __hip_atomic_load(&h1buf[prv * H + tid], __ATOMIC_RELAXED, __HIP_MEMORY_SCOPE_AGENT);
        __syncthreads();

        // ---- layer 1: gates = Wih1 @ h0(t) + Whh1 @ h1(t-1) + bias ----
        float acc1 = 0.0f;
        #pragma unroll
        for (int i = 0; i < 16; ++i) acc1 += w1[i] * hA[i * 32 + s] + w2[i] * hB[i * 32 + s];
        #pragma unroll
        for (int m = 16; m >= 1; m >>= 1) acc1 += __shfl_xor(acc1, m);
        if (s == 0) glds[group] = acc1 + bias1;
        __syncthreads();
        if (tid < UPB) {
            float iv = sigf(glds[tid]);
            float fv = sigf(glds[4 + tid]);
            float gv = tanhfast(glds[8 + tid]);
            float ov = sigf(glds[12 + tid]);
            c1 = fv * c1 + iv * gv;
            float h = ov * tanhfast(c1);
            __hip_atomic_store(&h1buf[cur * H + u0 + tid], h, __ATOMIC_RELEASE, __HIP_MEMORY_SCOPE_AGENT);
            h1n[tid] = h;
        }
        __syncthreads();
        if (tid == 0) {
            __hip_atomic_fetch_add(&cnt1[t], 1, __ATOMIC_RELEASE, __HIP_MEMORY_SCOPE_AGENT);
            float p = fmaxf(h1n[0], 0.f) * fw0 + fmaxf(h1n[1], 0.f) * fw1 +
                      fmaxf(h1n[2], 0.f) * fw2 + fmaxf(h1n[3], 0.f) * fw3;
            pout[(size_t)t * KBLK + b] = p;
        }
    }
}

// ---------------- reduce 128 partials per step -> out[t] ----------------
__global__ void reduce_out(const float* __restrict__ pout, const float* __restrict__ fcb,
                           float* __restrict__ out) {
    int t = blockIdx.x;
    int tid = threadIdx.x;                  // 128 threads
    float v = pout[(size_t)t * KBLK + tid];
    #pragma unroll
    for (int m = 32; m >= 1; m >>= 1) v += __shfl_xor(v, m);
    __shared__ float ws2[2];
    if ((tid & 63) == 0) ws2[tid >> 6] = v;
    __syncthreads();
    if (tid == 0) out[t] = ws2[0] + ws2[1] + fcb[0];
}

extern "C" void kernel_launch(void* const* d_in, const int* in_sizes, int n_in,
                              void* d_out, int out_size, void* d_ws, size_t ws_size,
                              hipStream_t stream) {
    const float* batch = (const float*)d_in[0];
    const float* Wih0  = (const float*)d_in[1];
    const float* Whh0  = (const float*)d_in[2];
    const float* bih0  = (const float*)d_in[3];
    const float* bhh0  = (const float*)d_in[4];
    const float* Wih1  = (const float*)d_in[5];   // [1,2048,512]
    const float* Whh1  = (const float*)d_in[6];
    const float* bih1  = (const float*)d_in[7];
    const float* bhh1  = (const float*)d_in[8];
    const float* lnw   = (const float*)d_in[9];
    const float* lnb   = (const float*)d_in[10];
    const float* fcw   = (const float*)d_in[11];
    const float* fcb   = (const float*)d_in[12];
    float* out = (float*)d_out;

    // workspace layout (~18.3 MB)
    float* ws    = (float*)d_ws;
    float* pre   = ws;                               // 2048*2048 f32
    float* lnx   = pre + (size_t)STEPS * G4;         // 2048*64
    float* pout  = lnx + (size_t)STEPS * WIN;        // 2048*128
    float* h0buf = pout + (size_t)STEPS * KBLK;      // 2*512
    float* h1buf = h0buf + 2 * H;                    // 2*512
    int*   cnt0  = (int*)(h1buf + 2 * H);            // 2048
    int*   cnt1  = cnt0 + STEPS;                     // 2048

    // zero h double-buffers + counters each call (contiguous region)
    hipMemsetAsync(h0buf, 0, (size_t)(4 * H) * sizeof(float) + 2 * STEPS * sizeof(int), stream);

    ln_kernel<<<dim3(STEPS / 4), dim3(256), 0, stream>>>(batch, lnw, lnb, lnx);
    precomp_kernel<<<dim3(G4 / 64, STEPS / 64), dim3(256), 0, stream>>>(Wih0, bih0, bhh0, lnx, pre);
    recur_kernel<<<dim3(KBLK), dim3(TPB), 0, stream>>>(Whh0, Wih1, Whh1, bih1, bhh1,
                                                       fcw, pre, h0buf, h1buf, cnt0, cnt1, pout);
    reduce_out<<<dim3(STEPS), dim3(KBLK), 0, stream>>>(pout, fcb, out);
}

// Round 2
// 9481.078 us; speedup vs baseline: 3.0316x; 3.0316x over previous
//
#include <hip/hip_runtime.h>
#include <math.h>

// LSTMModel: 2048 sequential steps, 2x LSTMCell(H=512), LN(64) front, fc(512->1).
// R1: sync-latency attack. Full h history (no WAR), two pipelined block groups
// (16 blocks layer0, 32 blocks layer1), per-group step counters, weights in regs.

#define H      512
#define G4     2048
#define WIN    64
#define STEPS  2048
#define NA     16      // layer-0 blocks (32 units each)
#define NB     32      // layer-1 blocks (16 units each)
#define TPB    512
#define ITERA  8       // 128 rows / 16 lane-groups
#define ITERB  4       // 64 rows / 16 lane-groups

__device__ __forceinline__ float sigf(float x)     { return 1.0f / (1.0f + __expf(-x)); }
__device__ __forceinline__ float tanhfast(float x) { return 2.0f / (1.0f + __expf(-2.0f * x)) - 1.0f; }

// ---------------- LayerNorm over sliding windows (parallel over t) ----------------
__global__ void ln_kernel(const float* __restrict__ batch, const float* __restrict__ lnw,
                          const float* __restrict__ lnb, float* __restrict__ lnx) {
    int wave = threadIdx.x >> 6;
    int lane = threadIdx.x & 63;
    int t = blockIdx.x * 4 + wave;
    int src = t - 63 + lane;
    float v = (src >= 0) ? batch[src] : 0.0f;
    float s = v, ss = v * v;
    #pragma unroll
    for (int m = 32; m >= 1; m >>= 1) { s += __shfl_xor(s, m); ss += __shfl_xor(ss, m); }
    float mu   = s * (1.0f / 64.0f);
    float var  = ss * (1.0f / 64.0f) - mu * mu;
    float rstd = rsqrtf(var + 1e-5f);
    lnx[t * WIN + lane] = (v - mu) * rstd * lnw[lane] + lnb[lane];
}

// ------------- precomp0[t][r] = Wih0[r,:] . lnx[t,:] + bih0[r] + bhh0[r] ----------
__global__ __launch_bounds__(256) void precomp_kernel(
    const float* __restrict__ Wih0, const float* __restrict__ bih0,
    const float* __restrict__ bhh0, const float* __restrict__ lnx,
    float* __restrict__ pre) {
    __shared__ float Wt[64][65];
    __shared__ float Xt[64][64];
    int r0 = blockIdx.x * 64;
    int t0 = blockIdx.y * 64;
    for (int i = threadIdx.x; i < 4096; i += 256) Wt[i >> 6][i & 63] = Wih0[r0 * 64 + i];
    for (int i = threadIdx.x; i < 4096; i += 256) Xt[i >> 6][i & 63] = lnx[t0 * 64 + i];
    __syncthreads();
    int lane = threadIdx.x & 63;
    int wv   = threadIdx.x >> 6;
    int row  = r0 + lane;
    float bias = bih0[row] + bhh0[row];
    for (int j = 0; j < 16; ++j) {
        int tl = wv * 16 + j;
        float acc = bias;
        #pragma unroll 8
        for (int k = 0; k < 64; ++k) acc += Wt[lane][k] * Xt[tl][k];
        pre[(size_t)(t0 + tl) * G4 + row] = acc;
    }
}

// ---------------- persistent recurrent kernel: two pipelined groups ----------------
__global__ __launch_bounds__(TPB, 2) void recur_kernel(
    const float* __restrict__ Whh0,
    const float* __restrict__ Wih1, const float* __restrict__ Whh1,
    const float* __restrict__ bih1, const float* __restrict__ bhh1,
    const float* __restrict__ fcw,  const float* __restrict__ pre,
    float* h0hist, float* h1hist,   // [STEPS+1][H]; slot k holds h(k-1), slot 0 = zeros
    int* cntA, int* cntB,           // per-step production counters
    float* __restrict__ pout) {     // [STEPS][NB] output partials
    const int tid = threadIdx.x;
    const int g   = tid >> 5;       // 16 lane-groups of 32
    const int s   = tid & 31;

    __shared__ float hA[H];
    __shared__ float hB[H];
    __shared__ float glds[128];
    __shared__ float preb[128];
    __shared__ float facc[16];

    if (blockIdx.x < NA) {
        // ---------------- layer-0 group: 32 units/block ----------------
        const int b  = blockIdx.x;
        const int u0 = b * 32;
        float w0[ITERA][16];
        #pragma unroll
        for (int j = 0; j < ITERA; ++j) {
            int r = j * 16 + g;                       // row-in-block = (unit<<2)|gate
            int grow = (r & 3) * H + u0 + (r >> 2);   // global gate row
            #pragma unroll
            for (int i = 0; i < 16; ++i)
                w0[j][i] = Whh0[(size_t)grow * H + i * 32 + s];
        }
        float c0 = 0.0f;

        for (int t = 0; t < STEPS; ++t) {
            // prefetch pre (independent of sync) while tid0 polls
            if (tid < 128) {
                int gate = tid >> 5, uu = tid & 31;
                preb[(uu << 2) | gate] = pre[(size_t)t * G4 + gate * H + u0 + uu];
            }
            if (t > 0 && tid == 0) {
                while (__hip_atomic_load(&cntA[t - 1], __ATOMIC_ACQUIRE, __HIP_MEMORY_SCOPE_AGENT) < NA) {}
            }
            __syncthreads();
            hA[tid] = __hip_atomic_load(&h0hist[(size_t)t * H + tid], __ATOMIC_RELAXED, __HIP_MEMORY_SCOPE_AGENT);
            __syncthreads();

            #pragma unroll
            for (int j = 0; j < ITERA; ++j) {
                float acc = 0.0f;
                #pragma unroll
                for (int i = 0; i < 16; ++i) acc += w0[j][i] * hA[i * 32 + s];
                #pragma unroll
                for (int m = 16; m >= 1; m >>= 1) acc += __shfl_xor(acc, m);
                if (s == 0) glds[j * 16 + g] = acc + preb[j * 16 + g];
            }
            __syncthreads();
            if (tid < 32) {
                float iv = sigf(glds[tid * 4 + 0]);
                float fv = sigf(glds[tid * 4 + 1]);
                float gv = tanhfast(glds[tid * 4 + 2]);
                float ov = sigf(glds[tid * 4 + 3]);
                c0 = fv * c0 + iv * gv;
                float h = ov * tanhfast(c0);
                __hip_atomic_store(&h0hist[(size_t)(t + 1) * H + u0 + tid], h,
                                   __ATOMIC_RELEASE, __HIP_MEMORY_SCOPE_AGENT);
            }
            __syncthreads();
            if (tid == 0)
                __hip_atomic_fetch_add(&cntA[t], 1, __ATOMIC_RELEASE, __HIP_MEMORY_SCOPE_AGENT);
        }
    } else {
        // ---------------- layer-1 group: 16 units/block ----------------
        const int b1 = blockIdx.x - NA;
        const int u0 = b1 * 16;
        float w1[ITERB][16], w2[ITERB][16], bias[ITERB];
        #pragma unroll
        for (int j = 0; j < ITERB; ++j) {
            int r = j * 16 + g;
            int grow = (r & 3) * H + u0 + (r >> 2);
            bias[j] = bih1[grow] + bhh1[grow];
            #pragma unroll
            for (int i = 0; i < 16; ++i) {
                w1[j][i] = Wih1[(size_t)grow * H + i * 32 + s];
                w2[j][i] = Whh1[(size_t)grow * H + i * 32 + s];
            }
        }
        float fcv = (tid < 16) ? fcw[u0 + tid] : 0.0f;
        float c1 = 0.0f;

        for (int t = 0; t < STEPS; ++t) {
            if (tid == 0) {
                while (__hip_atomic_load(&cntA[t], __ATOMIC_ACQUIRE, __HIP_MEMORY_SCOPE_AGENT) < NA) {}
                if (t > 0)
                    while (__hip_atomic_load(&cntB[t - 1], __ATOMIC_ACQUIRE, __HIP_MEMORY_SCOPE_AGENT) < NB) {}
            }
            __syncthreads();
            hA[tid] = __hip_atomic_load(&h0hist[(size_t)(t + 1) * H + tid], __ATOMIC_RELAXED, __HIP_MEMORY_SCOPE_AGENT);
            hB[tid] = __hip_atomic_load(&h1hist[(size_t)t * H + tid], __ATOMIC_RELAXED, __HIP_MEMORY_SCOPE_AGENT);
            __syncthreads();

            #pragma unroll
            for (int j = 0; j < ITERB; ++j) {
                float acc = 0.0f;
                #pragma unroll
                for (int i = 0; i < 16; ++i)
                    acc += w1[j][i] * hA[i * 32 + s] + w2[j][i] * hB[i * 32 + s];
                #pragma unroll
                for (int m = 16; m >= 1; m >>= 1) acc += __shfl_xor(acc, m);
                if (s == 0) glds[j * 16 + g] = acc + bias[j];
            }
            __syncthreads();
            if (tid < 16) {
                float iv = sigf(glds[tid * 4 + 0]);
                float fv = sigf(glds[tid * 4 + 1]);
                float gv = tanhfast(glds[tid * 4 + 2]);
                float ov = sigf(glds[tid * 4 + 3]);
                c1 = fv * c1 + iv * gv;
                float h = ov * tanhfast(c1);
                __hip_atomic_store(&h1hist[(size_t)(t + 1) * H + u0 + tid], h,
                                   __ATOMIC_RELEASE, __HIP_MEMORY_SCOPE_AGENT);
                facc[tid] = fmaxf(h, 0.0f) * fcv;
            }
            __syncthreads();
            if (tid == 0) {
                __hip_atomic_fetch_add(&cntB[t], 1, __ATOMIC_RELEASE, __HIP_MEMORY_SCOPE_AGENT);
                float p = 0.0f;
                #pragma unroll
                for (int u = 0; u < 16; ++u) p += facc[u];
                pout[(size_t)t * NB + b1] = p;
            }
        }
    }
}

// ---------------- reduce NB partials per step -> out[t] ----------------
__global__ void reduce_out(const float* __restrict__ pout, const float* __restrict__ fcb,
                           float* __restrict__ out) {
    int t = blockIdx.x;
    int l = threadIdx.x;                 // 64 threads
    float v = (l < NB) ? pout[(size_t)t * NB + l] : 0.0f;
    #pragma unroll
    for (int m = 16; m >= 1; m >>= 1) v += __shfl_xor(v, m);
    if (l == 0) out[t] = v + fcb[0];
}

extern "C" void kernel_launch(void* const* d_in, const int* in_sizes, int n_in,
                              void* d_out, int out_size, void* d_ws, size_t ws_size,
                              hipStream_t stream) {
    const float* batch = (const float*)d_in[0];
    const float* Wih0  = (const float*)d_in[1];
    const float* Whh0  = (const float*)d_in[2];
    const float* bih0  = (const float*)d_in[3];
    const float* bhh0  = (const float*)d_in[4];
    const float* Wih1  = (const float*)d_in[5];
    const float* Whh1  = (const float*)d_in[6];
    const float* bih1  = (const float*)d_in[7];
    const float* bhh1  = (const float*)d_in[8];
    const float* lnw   = (const float*)d_in[9];
    const float* lnb   = (const float*)d_in[10];
    const float* fcw   = (const float*)d_in[11];
    const float* fcb   = (const float*)d_in[12];
    float* out = (float*)d_out;

    // workspace layout (~25.3 MB)
    float* ws     = (float*)d_ws;
    float* pre    = ws;                                   // 2048*2048
    float* lnx    = pre + (size_t)STEPS * G4;             // 2048*64
    float* pout   = lnx + (size_t)STEPS * WIN;            // 2048*NB
    float* h0hist = pout + (size_t)STEPS * NB;            // (STEPS+1)*512
    float* h1hist = h0hist + (size_t)(STEPS + 1) * H;     // (STEPS+1)*512
    int*   cntA   = (int*)(h1hist + (size_t)(STEPS + 1) * H);  // 2048
    int*   cntB   = cntA + STEPS;                         // 2048

    hipMemsetAsync(h0hist, 0, H * sizeof(float), stream);        // h0(-1) = 0
    hipMemsetAsync(h1hist, 0, H * sizeof(float), stream);        // h1(-1) = 0
    hipMemsetAsync(cntA, 0, 2 * STEPS * sizeof(int), stream);    // cntA + cntB

    ln_kernel<<<dim3(STEPS / 4), dim3(256), 0, stream>>>(batch, lnw, lnb, lnx);
    precomp_kernel<<<dim3(G4 / 64, STEPS / 64), dim3(256), 0, stream>>>(Wih0, bih0, bhh0, lnx, pre);
    recur_kernel<<<dim3(NA + NB), dim3(TPB), 0, stream>>>(Whh0, Wih1, Whh1, bih1, bhh1,
                                                          fcw, pre, h0hist, h1hist, cntA, cntB, pout);
    reduce_out<<<dim3(STEPS), dim3(64), 0, stream>>>(pout, fcb, out);
}

// Round 3
// 6229.643 us; speedup vs baseline: 4.6138x; 1.5219x over previous
//
#include <hip/hip_runtime.h>
#include <math.h>

// LSTMModel: 2048 sequential steps, 2x LSTMCell(H=512), LN(64) front, fc(512->1).
// R2: data-as-flag sync. h histories poisoned with NaN (0xFFFFFFFF); consumers poll
// the exact word they need (no counters, no acquire/release hops). One syncthreads
// per step; per-unit gate rows grouped into one 32-lane group so gate nonlinearity
// is in-lane after the shuffle butterfly. LDS double-buffered by step parity.

#define H      512
#define G4     2048
#define WIN    64
#define STEPS  2048
#define NA     16      // layer-0 blocks (32 units each)
#define NB     32      // layer-1 blocks (16 units each)
#define TPB    512
#define POISON 0xFFFFFFFFu

__device__ __forceinline__ float sigf(float x)     { return 1.0f / (1.0f + __expf(-x)); }
__device__ __forceinline__ float tanhfast(float x) { return 2.0f / (1.0f + __expf(-2.0f * x)) - 1.0f; }

// ---------------- LayerNorm over sliding windows (parallel over t) ----------------
__global__ void ln_kernel(const float* __restrict__ batch, const float* __restrict__ lnw,
                          const float* __restrict__ lnb, float* __restrict__ lnx) {
    int wave = threadIdx.x >> 6;
    int lane = threadIdx.x & 63;
    int t = blockIdx.x * 4 + wave;
    int src = t - 63 + lane;
    float v = (src >= 0) ? batch[src] : 0.0f;
    float s = v, ss = v * v;
    #pragma unroll
    for (int m = 32; m >= 1; m >>= 1) { s += __shfl_xor(s, m); ss += __shfl_xor(ss, m); }
    float mu   = s * (1.0f / 64.0f);
    float var  = ss * (1.0f / 64.0f) - mu * mu;
    float rstd = rsqrtf(var + 1e-5f);
    lnx[t * WIN + lane] = (v - mu) * rstd * lnw[lane] + lnb[lane];
}

// ------------- precomp0[t][r] = Wih0[r,:] . lnx[t,:] + bih0[r] + bhh0[r] ----------
__global__ __launch_bounds__(256) void precomp_kernel(
    const float* __restrict__ Wih0, const float* __restrict__ bih0,
    const float* __restrict__ bhh0, const float* __restrict__ lnx,
    float* __restrict__ pre) {
    __shared__ float Wt[64][65];
    __shared__ float Xt[64][64];
    int r0 = blockIdx.x * 64;
    int t0 = blockIdx.y * 64;
    for (int i = threadIdx.x; i < 4096; i += 256) Wt[i >> 6][i & 63] = Wih0[r0 * 64 + i];
    for (int i = threadIdx.x; i < 4096; i += 256) Xt[i >> 6][i & 63] = lnx[t0 * 64 + i];
    __syncthreads();
    int lane = threadIdx.x & 63;
    int wv   = threadIdx.x >> 6;
    int row  = r0 + lane;
    float bias = bih0[row] + bhh0[row];
    for (int j = 0; j < 16; ++j) {
        int tl = wv * 16 + j;
        float acc = bias;
        #pragma unroll 8
        for (int k = 0; k < 64; ++k) acc += Wt[lane][k] * Xt[tl][k];
        pre[(size_t)(t0 + tl) * G4 + row] = acc;
    }
}

// ---------------- persistent recurrent kernel: two pipelined groups ----------------
__global__ __launch_bounds__(TPB) void recur_kernel(
    const float* __restrict__ Whh0,
    const float* __restrict__ Wih1, const float* __restrict__ Whh1,
    const float* __restrict__ bih1, const float* __restrict__ bhh1,
    const float* __restrict__ fcw,  const float* __restrict__ pre,
    unsigned int* h0u, unsigned int* h1u,  // [STEPS+1][H] histories, NaN-poisoned
    float* __restrict__ pout) {            // [STEPS][NB] output partials
    const int tid = threadIdx.x;
    const int s   = tid & 31;
    const int LG  = tid >> 5;    // 16 lane-groups of 32

    if (blockIdx.x < NA) {
        // ---------------- layer-0: 32 units/block ----------------
        __shared__ float hA[2][H];
        __shared__ float preb[2][128];   // [gate][unit_local] layout, parity-buffered
        const int u0 = blockIdx.x * 32;
        // rows: j=0..7 -> gate=j&3, unit_local=2*LG+(j>>2)
        float w0[8][16];
        #pragma unroll
        for (int j = 0; j < 8; ++j) {
            int row = (j & 3) * H + u0 + 2 * LG + (j >> 2);
            #pragma unroll
            for (int i = 0; i < 16; ++i) w0[j][i] = Whh0[(size_t)row * H + i * 32 + s];
        }
        float c0 = 0.0f;

        for (int t = 0; t < STEPS; ++t) {
            const int pb = t & 1;
            if (tid < 128)
                preb[pb][tid] = pre[(size_t)t * G4 + (tid >> 5) * H + u0 + (tid & 31)];
            if (t > 0) {
                unsigned int bits;
                do {
                    bits = __hip_atomic_load(&h0u[(size_t)t * H + tid],
                                             __ATOMIC_RELAXED, __HIP_MEMORY_SCOPE_AGENT);
                } while (bits == POISON);
                hA[pb][tid] = __uint_as_float(bits);
            } else {
                hA[pb][tid] = 0.0f;
            }
            __syncthreads();

            float acc[8];
            #pragma unroll
            for (int j = 0; j < 8; ++j) {
                float a = 0.0f;
                #pragma unroll
                for (int i = 0; i < 16; ++i) a += w0[j][i] * hA[pb][i * 32 + s];
                acc[j] = a;
            }
            #pragma unroll
            for (int m = 16; m >= 1; m >>= 1) {
                #pragma unroll
                for (int j = 0; j < 8; ++j) acc[j] += __shfl_xor(acc[j], m);
            }
            if (s < 2) {
                int ul = 2 * LG + s;
                int base = s * 4;
                float iv = sigf(acc[base + 0] + preb[pb][0 * 32 + ul]);
                float fv = sigf(acc[base + 1] + preb[pb][1 * 32 + ul]);
                float gv = tanhfast(acc[base + 2] + preb[pb][2 * 32 + ul]);
                float ov = sigf(acc[base + 3] + preb[pb][3 * 32 + ul]);
                c0 = fv * c0 + iv * gv;
                float h = ov * tanhfast(c0);
                __hip_atomic_store(&h0u[(size_t)(t + 1) * H + u0 + ul], __float_as_uint(h),
                                   __ATOMIC_RELAXED, __HIP_MEMORY_SCOPE_AGENT);
            }
        }
    } else {
        // ---------------- layer-1: 16 units/block ----------------
        __shared__ float hA[2][H];
        __shared__ float hB[2][H];
        __shared__ float facc[16];
        const int b1 = blockIdx.x - NA;
        const int u0 = b1 * 16;
        // rows: j = gate 0..3, unit_local = LG
        float w1[4][16], w2[4][16], bias[4];
        #pragma unroll
        for (int j = 0; j < 4; ++j) {
            int row = j * H + u0 + LG;
            bias[j] = bih1[row] + bhh1[row];
            #pragma unroll
            for (int i = 0; i < 16; ++i) {
                w1[j][i] = Wih1[(size_t)row * H + i * 32 + s];
                w2[j][i] = Whh1[(size_t)row * H + i * 32 + s];
            }
        }
        const float fcv = fcw[u0 + LG];
        float c1 = 0.0f;

        for (int t = 0; t < STEPS; ++t) {
            const int pb = t & 1;
            {
                unsigned int bits;
                do {
                    bits = __hip_atomic_load(&h0u[(size_t)(t + 1) * H + tid],
                                             __ATOMIC_RELAXED, __HIP_MEMORY_SCOPE_AGENT);
                } while (bits == POISON);
                hA[pb][tid] = __uint_as_float(bits);
            }
            if (t > 0) {
                unsigned int bits;
                do {
                    bits = __hip_atomic_load(&h1u[(size_t)t * H + tid],
                                             __ATOMIC_RELAXED, __HIP_MEMORY_SCOPE_AGENT);
                } while (bits == POISON);
                hB[pb][tid] = __uint_as_float(bits);
            } else {
                hB[pb][tid] = 0.0f;
            }
            __syncthreads();

            float acc[4];
            #pragma unroll
            for (int j = 0; j < 4; ++j) {
                float a = 0.0f;
                #pragma unroll
                for (int i = 0; i < 16; ++i)
                    a += w1[j][i] * hA[pb][i * 32 + s] + w2[j][i] * hB[pb][i * 32 + s];
                acc[j] = a;
            }
            #pragma unroll
            for (int m = 16; m >= 1; m >>= 1) {
                #pragma unroll
                for (int j = 0; j < 4; ++j) acc[j] += __shfl_xor(acc[j], m);
            }
            if (s == 0) {
                float iv = sigf(acc[0] + bias[0]);
                float fv = sigf(acc[1] + bias[1]);
                float gv = tanhfast(acc[2] + bias[2]);
                float ov = sigf(acc[3] + bias[3]);
                c1 = fv * c1 + iv * gv;
                float h = ov * tanhfast(c1);
                __hip_atomic_store(&h1u[(size_t)(t + 1) * H + u0 + LG], __float_as_uint(h),
                                   __ATOMIC_RELAXED, __HIP_MEMORY_SCOPE_AGENT);
                facc[LG] = fmaxf(h, 0.0f) * fcv;
            }
            __syncthreads();
            if (tid == 0) {
                float p = 0.0f;
                #pragma unroll
                for (int u = 0; u < 16; ++u) p += facc[u];
                pout[(size_t)t * NB + b1] = p;
            }
        }
    }
}

// ---------------- reduce NB partials per step -> out[t] ----------------
__global__ void reduce_out(const float* __restrict__ pout, const float* __restrict__ fcb,
                           float* __restrict__ out) {
    int t = blockIdx.x;
    int l = threadIdx.x;                 // 64 threads
    float v = (l < NB) ? pout[(size_t)t * NB + l] : 0.0f;
    #pragma unroll
    for (int m = 16; m >= 1; m >>= 1) v += __shfl_xor(v, m);
    if (l == 0) out[t] = v + fcb[0];
}

extern "C" void kernel_launch(void* const* d_in, const int* in_sizes, int n_in,
                              void* d_out, int out_size, void* d_ws, size_t ws_size,
                              hipStream_t stream) {
    const float* batch = (const float*)d_in[0];
    const float* Wih0  = (const float*)d_in[1];
    const float* Whh0  = (const float*)d_in[2];
    const float* bih0  = (const float*)d_in[3];
    const float* bhh0  = (const float*)d_in[4];
    const float* Wih1  = (const float*)d_in[5];
    const float* Whh1  = (const float*)d_in[6];
    const float* bih1  = (const float*)d_in[7];
    const float* bhh1  = (const float*)d_in[8];
    const float* lnw   = (const float*)d_in[9];
    const float* lnb   = (const float*)d_in[10];
    const float* fcw   = (const float*)d_in[11];
    const float* fcb   = (const float*)d_in[12];
    float* out = (float*)d_out;

    // workspace layout (~25.3 MB)
    float*        ws     = (float*)d_ws;
    float*        pre    = ws;                                    // 2048*2048
    float*        lnx    = pre + (size_t)STEPS * G4;              // 2048*64
    float*        pout   = lnx + (size_t)STEPS * WIN;             // 2048*NB
    unsigned int* h0u    = (unsigned int*)(pout + (size_t)STEPS * NB);  // (STEPS+1)*512
    unsigned int* h1u    = h0u + (size_t)(STEPS + 1) * H;         // (STEPS+1)*512

    // poison both h histories (NaN pattern); slot 0 handled by t==0 branch in-kernel
    hipMemsetAsync(h0u, 0xFF, (size_t)2 * (STEPS + 1) * H * sizeof(unsigned int), stream);

    ln_kernel<<<dim3(STEPS / 4), dim3(256), 0, stream>>>(batch, lnw, lnb, lnx);
    precomp_kernel<<<dim3(G4 / 64, STEPS / 64), dim3(256), 0, stream>>>(Wih0, bih0, bhh0, lnx, pre);
    recur_kernel<<<dim3(NA + NB), dim3(TPB), 0, stream>>>(Whh0, Wih1, Whh1, bih1, bhh1,
                                                          fcw, pre, h0u, h1u, pout);
    reduce_out<<<dim3(STEPS), dim3(64), 0, stream>>>(pout, fcb, out);
}